// Round 17
// baseline (594.059 us; speedup 1.0000x reference)
//
#include <hip/hip_runtime.h>
#include <math.h>

namespace {

constexpr int Bn = 4;
constexpr int H0 = 256, W0 = 448;
constexpr int H1 = 128, W1 = 224;
constexpr int H2 = 64,  W2 = 112;
constexpr int HW0 = H0 * W0;
constexpr int CAP = 8;           // global bin capacity (mean 1/cell)
constexpr int OVCAP = 8192;      // per-level overflow list
constexpr int NC0 = (W0 + 1) * (H0 + 1);   // padded cell grids
constexpr int NC1 = (W1 + 1) * (H1 + 1);
constexpr int NC2 = (W2 + 1) * (H2 + 1);

// np.linspace(-1+1/n, 1-1/n, n, dtype=f32) bit path (backwarp side; validated).
__device__ inline float lin_ac_f32(int i, int n) {
    if (i == n - 1) return (float)(1.0 - 1.0 / (double)n);
    double start = -1.0 + 1.0 / (double)n;
    double step  = (2.0 - 2.0 / (double)n) / (double)(n - 1);
    return (float)(start + (double)i * step);
}

// ---------------------------------------------------------------------------
// Backwarp + L1 occlusion metric, both directions in one launch (validated
// bit path, dir only selects pointers).
// ---------------------------------------------------------------------------
__global__ __launch_bounds__(256) void metric2_kernel(
        const float* __restrict__ img1, const float* __restrict__ img2,
        const float* __restrict__ fl12, const float* __restrict__ fl21,
        float* __restrict__ m12, float* __restrict__ m21) {
    int idx = blockIdx.x * 256 + threadIdx.x;
    int total = 2 * Bn * HW0;
    if (idx >= total) return;
    int dir = idx / (Bn * HW0);
    int sub = idx % (Bn * HW0);
    const float* imgA = dir ? img2 : img1;
    const float* imgB = dir ? img1 : img2;
    const float* flow = dir ? fl21 : fl12;
    float* mout = dir ? m21 : m12;

    int x = sub % W0;
    int y = (sub / W0) % H0;
    int b = sub / HW0;

    const float* fb = flow + (size_t)b * 2 * HW0;
    float fx = fb[y * W0 + x];
    float fy = fb[(size_t)HW0 + y * W0 + x];

    const float sxc = (float)(2.0 / (double)(W0 - 1));
    const float syc = (float)(2.0 / (double)(H0 - 1));
    float gx = __fadd_rn(lin_ac_f32(x, W0), __fmul_rn(fx, sxc));
    float gy = __fadd_rn(lin_ac_f32(y, H0), __fmul_rn(fy, syc));
    float px = __fmul_rn(__fmul_rn(__fadd_rn(gx, 1.0f), 0.5f), (float)(W0 - 1));
    float py = __fmul_rn(__fmul_rn(__fadd_rn(gy, 1.0f), 0.5f), (float)(H0 - 1));

    float x0f = floorf(px), y0f = floorf(py);
    float x1f = x0f + 1.0f, y1f = y0f + 1.0f;
    int x0 = (int)x0f, y0 = (int)y0f, x1 = (int)x1f, y1 = (int)y1f;

    float tw[4] = { (x1f - px) * (y1f - py), (px - x0f) * (y1f - py),
                    (x1f - px) * (py - y0f), (px - x0f) * (py - y0f) };
    int tx[4] = { x0, x1, x0, x1 };
    int ty[4] = { y0, y0, y1, y1 };

    const float* ib = imgB + (size_t)b * 3 * HW0;
    float acc0 = 0.f, acc1 = 0.f, acc2 = 0.f;
#pragma unroll
    for (int t = 0; t < 4; ++t) {
        bool valid = (tx[t] >= 0) && (tx[t] < W0) && (ty[t] >= 0) && (ty[t] < H0);
        int xc = min(max(tx[t], 0), W0 - 1);
        int yc = min(max(ty[t], 0), H0 - 1);
        float ww = valid ? tw[t] : 0.f;
        int off = yc * W0 + xc;
        acc0 += ib[off] * ww;
        acc1 += ib[(size_t)HW0 + off] * ww;
        acc2 += ib[(size_t)2 * HW0 + off] * ww;
    }
    const float* ia = imgA + (size_t)b * 3 * HW0;
    int off = y * W0 + x;
    float m = (fabsf(ia[off] - acc0) +
               fabsf(ia[(size_t)HW0 + off] - acc1) +
               fabsf(ia[(size_t)2 * HW0 + off] - acc2)) * (1.f / 3.f);
    mout[(size_t)b * HW0 + off] = m;
}

// jax-f32 linspace bit path + endpoint forcing (validated round 6).
__device__ inline void ac32_iota(int i, int n_in, int n_out, float delta,
                                 int& i0, int& i1, float& fr) {
    float v = (i == n_out - 1) ? (float)(n_in - 1) : __fmul_rn(delta, (float)i);
    float f0 = floorf(v);
    i0 = (int)f0;
    i1 = min(i0 + 1, n_in - 1);
    fr = __fsub_rn(v, f0);
}

// Unfused pinned f32 bilinear (validated round 6).
__device__ inline float bilerp32(const float* __restrict__ s, int Win,
                                 int y0, int y1, int x0, int x1,
                                 float wy, float wx) {
    float a = s[y0 * Win + x0], b = s[y1 * Win + x0];
    float c = s[y0 * Win + x1], d = s[y1 * Win + x1];
    float omwy = __fsub_rn(1.0f, wy), omwx = __fsub_rn(1.0f, wx);
    float r0 = __fadd_rn(__fmul_rn(a, omwy), __fmul_rn(b, wy));
    float r1 = __fadd_rn(__fmul_rn(c, omwy), __fmul_rn(d, wy));
    return __fadd_rn(__fmul_rn(r0, omwx), __fmul_rn(r1, wx));
}

// chunked XCD swizzle (grid divisible by 8)
__device__ inline int swz_block(int bid, int nblk) {
    int cpx = nblk >> 3;
    return (bid & 7) * cpx + (bid >> 3);
}

// ---------------------------------------------------------------------------
// Lean geometry: source -> {gx, gy, cell x0/y0} — EXACT round-6 bit paths.
// ---------------------------------------------------------------------------
template<int LVL>
struct Geo {
    float gx, gy;
    int x0, y0;
    int ry0, ry1, rx0, rx1;
    float wy, wx;
};

template<int LVL>
__device__ inline Geo<LVL> geom(int x, int y, int b, int h, int w,
                                const float* __restrict__ flow,
                                float scale, float dly, float dlx) {
    Geo<LVL> g;
    float gx, gy;
    if constexpr (LVL == 0) {
        const float* fb = flow + (size_t)b * 2 * HW0;
        float fx = 0.5f * fb[y * W0 + x];
        float fy = 0.5f * fb[(size_t)HW0 + y * W0 + x];
        gx = (float)x + fx;
        gy = (float)y + fy;
    } else {
        ac32_iota(y, H0, h, dly, g.ry0, g.ry1, g.wy);
        ac32_iota(x, W0, w, dlx, g.rx0, g.rx1, g.wx);
        const float* fB = flow + (size_t)b * 2 * HW0;
        float fx = __fmul_rn(bilerp32(fB, W0, g.ry0, g.ry1, g.rx0, g.rx1, g.wy, g.wx), scale);
        float fy = __fmul_rn(bilerp32(fB + (size_t)HW0, W0, g.ry0, g.ry1, g.rx0, g.rx1, g.wy, g.wx), scale);
        gx = __fadd_rn((float)x, fx);
        gy = __fadd_rn((float)y, fy);
    }
    g.gx = gx; g.gy = gy;
    g.x0 = (int)floorf(gx);
    g.y0 = (int)floorf(gy);
    return g;
}

// Tap weight from stored gx/gy — identical pinned tail as validated R16
// phase 2. t: 0=(x0,y0) 1=(x0+1,y0) 2=(x0,y0+1) 3=(x0+1,y0+1).
template<int LVL>
__device__ inline float tap_w(float gx, float gy, int t) {
    float x0f = floorf(gx), y0f = floorf(gy);
    if constexpr (LVL == 0) {
        float x1f = x0f + 1.f, y1f = y0f + 1.f;
        return (t == 0) ? (x1f - gx) * (y1f - gy)
             : (t == 1) ? (gx - x0f) * (y1f - gy)
             : (t == 2) ? (x1f - gx) * (gy - y0f)
                        : (gx - x0f) * (gy - y0f);
    } else {
        float x1f = __fadd_rn(x0f, 1.0f), y1f = __fadd_rn(y0f, 1.0f);
        float dx0 = __fsub_rn(x1f, gx), dx1 = __fsub_rn(gx, x0f);
        float dy0 = __fsub_rn(y1f, gy), dy1 = __fsub_rn(gy, y0f);
        return (t == 0) ? __fmul_rn(dx0, dy0)
             : (t == 1) ? __fmul_rn(dx1, dy0)
             : (t == 2) ? __fmul_rn(dx0, dy1)
                        : __fmul_rn(dx1, dy1);
    }
}

// ---------------------------------------------------------------------------
// Global binning: ONE geom+wgt per source (both dirs in one launch); entry
// {gx, gy, wgt, sidx} scattered into the padded cell grid. Replaces both the
// irr kernels and all per-tile window scans.
// ---------------------------------------------------------------------------
template<int LVL, int H, int W, int NC>
__global__ __launch_bounds__(256) void bin_kernel(
        const float* __restrict__ fl12, const float* __restrict__ fl21,
        const float* __restrict__ m12, const float* __restrict__ m21,
        const float* __restrict__ alphap,
        int* __restrict__ cnt, float4* __restrict__ ent,
        int* __restrict__ ovn, int* __restrict__ ovkey, float4* __restrict__ ovdata,
        float scale, float dly, float dlx) {
    int idx = blockIdx.x * 256 + threadIdx.x;
    int total = 2 * Bn * H * W;
    if (idx >= total) return;
    int dir = idx / (Bn * H * W);
    int sub = idx % (Bn * H * W);
    const float* flow = dir ? fl21 : fl12;
    const float* met  = dir ? m21 : m12;
    int x = sub % W, y = (sub / W) % H, b = sub / (H * W);

    Geo<LVL> g = geom<LVL>(x, y, b, H, W, flow, scale, dly, dlx);
    if (g.x0 < -1 || g.x0 > W - 1 || g.y0 < -1 || g.y0 > H - 1) return;

    float a = alphap[0];
    float wgt;
    if constexpr (LVL == 0) wgt = expf(a * met[(size_t)b * HW0 + y * W0 + x]);
    else {
        float m = bilerp32(met + (size_t)b * HW0, W0, g.ry0, g.ry1, g.rx0, g.rx1, g.wy, g.wx);
        wgt = expf(__fmul_rn(a, m));
    }

    int cell = (g.y0 + 1) * (W + 1) + (g.x0 + 1);
    int slot = (dir * Bn + b) * NC + cell;
    float4 e;
    e.x = g.gx; e.y = g.gy; e.z = wgt; e.w = __int_as_float(y * W + x);
    int pos = atomicAdd(&cnt[slot], 1);
    if (pos < CAP) ent[(size_t)slot * CAP + pos] = e;
    else {
        int p2 = atomicAdd(ovn, 1);
        if (p2 < OVCAP) { ovkey[p2] = slot; ovdata[p2] = e; }
    }
}

// ---------------------------------------------------------------------------
// NCHW -> NHWC transpose (values only; validated, unchanged).
// ---------------------------------------------------------------------------
template<int CH>
__global__ __launch_bounds__(256) void transpose_kernel(const float* __restrict__ src0, int C0,
                                                        const float* __restrict__ src1, int C1,
                                                        float* __restrict__ dst, int HW) {
    __shared__ float lds[128 * CH];
    int gp = blockIdx.x * 128;
    int b = gp / HW, p0 = gp % HW;
    int tid = threadIdx.x;
    int CT = C0 + C1;
    for (int i = tid; i < 128 * CH; i += 256) {
        int c = i / 128, p = i % 128;
        float v = 0.f;
        if (c < C0) v = src0[((size_t)b * C0 + c) * HW + p0 + p];
        else if (c < CT) v = src1[((size_t)b * C1 + (c - C0)) * HW + p0 + p];
        lds[p * CH + c] = v;
    }
    __syncthreads();
    float4* d4 = (float4*)(dst + (size_t)gp * CH);
    const int N4 = 128 * CH / 4;
    for (int i = tid; i < N4; i += 256) {
        int base = i * 4;
        float4 q = { lds[base], lds[base + 1], lds[base + 2], lds[base + 3] };
        d4[i] = q;
    }
}

// ---------------------------------------------------------------------------
// Gather: zero scanning. Each thread = (pixel, channel-half); reads its 4
// neighbor cells' binned entries (1 float4 each), recomputes the tap weight
// bit-identically (compile-time t), accumulates NHWC float4s in registers,
// normalizes, writes NCHW. No LDS, no atomics.
// ---------------------------------------------------------------------------
template<int LVL, int CREAL, int CBT4, int NV0, int NV1, int H, int W, int NC>
__global__ __launch_bounds__(512) void gather_kernel(
        const float4* __restrict__ nhwc,
        const int* __restrict__ cnt, const float4* __restrict__ ent,
        const int* __restrict__ ovn_p, const int* __restrict__ ovkey,
        const float4* __restrict__ ovdata,
        float* __restrict__ outp, int Cout, int cbase, int dir) {
    constexpr int NVM = (NV0 > NV1) ? NV0 : NV1;
    constexpr int HW_ = H * W;
    int blk = swz_block(blockIdx.x, gridDim.x);
    int pixel = blk * 256 + (threadIdx.x & 255);
    int half = threadIdx.x >> 8;
    int b = pixel / HW_;
    int p = pixel % HW_;
    int px = p % W, py = p / W;
    int voff = half ? NV0 : 0;
    int nv = half ? NV1 : NV0;
    const float4* nbp = nhwc + (size_t)b * HW_ * CBT4 + voff;
    int base = (dir * Bn + b) * NC;

    float ax[NVM], ay[NVM], az[NVM], aw[NVM];
#pragma unroll
    for (int vi = 0; vi < NVM; ++vi) { ax[vi] = 0.f; ay[vi] = 0.f; az[vi] = 0.f; aw[vi] = 0.f; }
    float wacc = 0.f;

#pragma unroll
    for (int cyi = 0; cyi < 2; ++cyi)
#pragma unroll
    for (int cxi = 0; cxi < 2; ++cxi) {
        const int t = (1 - cyi) * 2 + (1 - cxi);
        int cx = px - 1 + cxi, cy = py - 1 + cyi;     // always within padded grid
        int slot = base + (cy + 1) * (W + 1) + (cx + 1);
        int n = min(cnt[slot], CAP);
        for (int j = 0; j < n; ++j) {
            float4 e = ent[(size_t)slot * CAP + j];
            float tw = tap_w<LVL>(e.x, e.y, t);
            float wgt = e.z;
            const float4* vp = nbp + (size_t)__float_as_int(e.w) * CBT4;
            if constexpr (LVL == 0) {
                float twv = tw * wgt;
                wacc += twv;
#pragma unroll
                for (int vi = 0; vi < NVM; ++vi) {
                    if (vi >= nv) break;
                    float4 q = vp[vi];
                    ax[vi] += q.x * twv; ay[vi] += q.y * twv;
                    az[vi] += q.z * twv; aw[vi] += q.w * twv;
                }
            } else {
                wacc += __fmul_rn(wgt, tw);
#pragma unroll
                for (int vi = 0; vi < NVM; ++vi) {
                    if (vi >= nv) break;
                    float4 q = vp[vi];
                    ax[vi] += __fmul_rn(__fmul_rn(q.x, wgt), tw);
                    ay[vi] += __fmul_rn(__fmul_rn(q.y, wgt), tw);
                    az[vi] += __fmul_rn(__fmul_rn(q.z, wgt), tw);
                    aw[vi] += __fmul_rn(__fmul_rn(q.w, wgt), tw);
                }
            }
        }
    }

    // overflow entries (expected ~0)
    int novr = min(ovn_p[0], OVCAP);
    for (int j = 0; j < novr; ++j) {
        int key = ovkey[j];
        int t = -1;
#pragma unroll
        for (int cyi = 0; cyi < 2; ++cyi)
#pragma unroll
        for (int cxi = 0; cxi < 2; ++cxi) {
            int slot = base + (py - 1 + cyi + 1) * (W + 1) + (px - 1 + cxi + 1);
            if (key == slot) t = (1 - cyi) * 2 + (1 - cxi);
        }
        if (t < 0) continue;
        float4 e = ovdata[j];
        float tw = tap_w<LVL>(e.x, e.y, t);
        float wgt = e.z;
        const float4* vp = nbp + (size_t)__float_as_int(e.w) * CBT4;
        if constexpr (LVL == 0) {
            float twv = tw * wgt;
            wacc += twv;
#pragma unroll
            for (int vi = 0; vi < NVM; ++vi) {
                if (vi >= nv) break;
                float4 q = vp[vi];
                ax[vi] += q.x * twv; ay[vi] += q.y * twv;
                az[vi] += q.z * twv; aw[vi] += q.w * twv;
            }
        } else {
            wacc += __fmul_rn(wgt, tw);
#pragma unroll
            for (int vi = 0; vi < NVM; ++vi) {
                if (vi >= nv) break;
                float4 q = vp[vi];
                ax[vi] += __fmul_rn(__fmul_rn(q.x, wgt), tw);
                ay[vi] += __fmul_rn(__fmul_rn(q.y, wgt), tw);
                az[vi] += __fmul_rn(__fmul_rn(q.z, wgt), tw);
                aw[vi] += __fmul_rn(__fmul_rn(q.w, wgt), tw);
            }
        }
    }

    float denom = wacc + 1e-7f;
    size_t obase = ((size_t)b * Cout + cbase) * HW_ + (py * W + px);
#pragma unroll
    for (int vi = 0; vi < NVM; ++vi) {
        if (vi >= nv) break;
        int c0 = (voff + vi) * 4;
        if (c0 + 0 < CREAL) outp[obase + (size_t)(c0 + 0) * HW_] = ax[vi] / denom;
        if (c0 + 1 < CREAL) outp[obase + (size_t)(c0 + 1) * HW_] = ay[vi] / denom;
        if (c0 + 2 < CREAL) outp[obase + (size_t)(c0 + 2) * HW_] = az[vi] / denom;
        if (c0 + 3 < CREAL) outp[obase + (size_t)(c0 + 3) * HW_] = aw[vi] / denom;
    }
}

inline int nblk(long long n) { return (int)((n + 255) / 256); }

} // namespace

extern "C" void kernel_launch(void* const* d_in, const int* in_sizes, int n_in,
                              void* d_out, int out_size, void* d_ws, size_t ws_size,
                              hipStream_t stream) {
    const float* img1 = (const float*)d_in[0];
    const float* img2 = (const float*)d_in[1];
    const float* f1_1 = (const float*)d_in[2];
    const float* f1_2 = (const float*)d_in[3];
    const float* f1_3 = (const float*)d_in[4];
    const float* f2_1 = (const float*)d_in[5];
    const float* f2_2 = (const float*)d_in[6];
    const float* f2_3 = (const float*)d_in[7];
    const float* fl12 = (const float*)d_in[8];
    const float* fl21 = (const float*)d_in[9];
    const float* alpha = (const float*)d_in[10];
    float* out = (float*)d_out;

    const float dy1 = (float)(H0 - 1) / (float)(H1 - 1);
    const float dx1 = (float)(W0 - 1) / (float)(W1 - 1);
    const float dy2 = (float)(H0 - 1) / (float)(H2 - 1);
    const float dx2 = (float)(W0 - 1) / (float)(W2 - 1);

    // ---- workspace layout (float4 arrays first for alignment) ----
    float4* entL0  = (float4*)d_ws;                        // 8*NC0*CAP  (118 MB)
    float4* entL1  = entL0 + (size_t)8 * NC0 * CAP;        // 29.7 MB
    float4* entL2  = entL1 + (size_t)8 * NC1 * CAP;        // 7.5 MB
    float4* ovdata = entL2 + (size_t)8 * NC2 * CAP;        // 3*OVCAP
    float*  nhwcW  = (float*)(ovdata + 3 * OVCAP);         // 29.4 MB (L1/L2 reuse)
    float*  m12    = nhwcW + (size_t)Bn * H1 * W1 * 64;
    float*  m21    = m12 + (size_t)Bn * HW0;
    int*    cnt0   = (int*)(m21 + (size_t)Bn * HW0);       // 8*NC0
    int*    cnt1   = cnt0 + (size_t)8 * NC0;
    int*    cnt2   = cnt1 + (size_t)8 * NC1;
    int*    ovn    = cnt2 + (size_t)8 * NC2;               // 16 ints (3 used)
    int*    ovkey  = ovn + 16;                             // 3*OVCAP ints
    size_t zero_bytes = ((size_t)8 * (NC0 + NC1 + NC2) + 16) * sizeof(int);

    float* l1 = out;
    float* l2 = l1 + (size_t)Bn * 70 * HW0;
    float* nhwc0 = l2;                                     // L0 NHWC in unwritten l2+l3
    float* l3 = l2 + (size_t)Bn * 128 * (H1 * W1);

    (void)hipMemsetAsync(cnt0, 0, zero_bytes, stream);

    // ---- metrics (both dirs, 1 launch) ----
    metric2_kernel<<<nblk((long long)2 * Bn * HW0), 256, 0, stream>>>(
        img1, img2, fl12, fl21, m12, m21);

    // ---- global binning (both dirs per level) ----
    bin_kernel<0, H0, W0, NC0><<<2 * Bn * HW0 / 256, 256, 0, stream>>>(
        fl12, fl21, m12, m21, alpha, cnt0, entL0, ovn + 0, ovkey, ovdata, 0.f, 0.f, 0.f);
    bin_kernel<1, H1, W1, NC1><<<2 * Bn * H1 * W1 / 256, 256, 0, stream>>>(
        fl12, fl21, m12, m21, alpha, cnt1, entL1, ovn + 1, ovkey + OVCAP, ovdata + OVCAP,
        0.25f, dy1, dx1);
    bin_kernel<1, H2, W2, NC2><<<2 * Bn * H2 * W2 / 256, 256, 0, stream>>>(
        fl12, fl21, m12, m21, alpha, cnt2, entL2, ovn + 2, ovkey + 2 * OVCAP, ovdata + 2 * OVCAP,
        0.125f, dy2, dx2);

    const int GT0 = Bn * HW0 / 128, GT1 = Bn * H1 * W1 / 128, GT2 = Bn * H2 * W2 / 128;
    const int GG0 = Bn * HW0 / 256, GG1 = Bn * H1 * W1 / 256, GG2 = Bn * H2 * W2 / 256;

    // ================= level 0 =================
    transpose_kernel<36><<<GT0, 256, 0, stream>>>(img1, 3, f1_1, 32, nhwc0, HW0);
    gather_kernel<0, 35, 9, 5, 4, H0, W0, NC0><<<GG0, 512, 0, stream>>>(
        (const float4*)nhwc0, cnt0, entL0, ovn + 0, ovkey, ovdata, l1, 70, 0, 0);
    transpose_kernel<36><<<GT0, 256, 0, stream>>>(img2, 3, f2_1, 32, nhwc0, HW0);
    gather_kernel<0, 35, 9, 5, 4, H0, W0, NC0><<<GG0, 512, 0, stream>>>(
        (const float4*)nhwc0, cnt0, entL0, ovn + 0, ovkey, ovdata, l1, 70, 35, 1);

    // ================= level 1 =================
    transpose_kernel<64><<<GT1, 256, 0, stream>>>(f1_2, 64, nullptr, 0, nhwcW, H1 * W1);
    gather_kernel<1, 64, 16, 8, 8, H1, W1, NC1><<<GG1, 512, 0, stream>>>(
        (const float4*)nhwcW, cnt1, entL1, ovn + 1, ovkey + OVCAP, ovdata + OVCAP,
        l2, 128, 0, 0);
    transpose_kernel<64><<<GT1, 256, 0, stream>>>(f2_2, 64, nullptr, 0, nhwcW, H1 * W1);
    gather_kernel<1, 64, 16, 8, 8, H1, W1, NC1><<<GG1, 512, 0, stream>>>(
        (const float4*)nhwcW, cnt1, entL1, ovn + 1, ovkey + OVCAP, ovdata + OVCAP,
        l2, 128, 64, 1);

    // ================= level 2 =================
    transpose_kernel<96><<<GT2, 256, 0, stream>>>(f1_3, 96, nullptr, 0, nhwcW, H2 * W2);
    gather_kernel<1, 96, 24, 12, 12, H2, W2, NC2><<<GG2, 512, 0, stream>>>(
        (const float4*)nhwcW, cnt2, entL2, ovn + 2, ovkey + 2 * OVCAP, ovdata + 2 * OVCAP,
        l3, 192, 0, 0);
    transpose_kernel<96><<<GT2, 256, 0, stream>>>(f2_3, 96, nullptr, 0, nhwcW, H2 * W2);
    gather_kernel<1, 96, 24, 12, 12, H2, W2, NC2><<<GG2, 512, 0, stream>>>(
        (const float4*)nhwcW, cnt2, entL2, ovn + 2, ovkey + 2 * OVCAP, ovdata + 2 * OVCAP,
        l3, 192, 96, 1);
}

// Round 18
// 555.904 us; speedup vs baseline: 1.0686x; 1.0686x over previous
//
#include <hip/hip_runtime.h>
#include <math.h>

namespace {

constexpr int Bn = 4;
constexpr int H0 = 256, W0 = 448;
constexpr int H1 = 128, W1 = 224;
constexpr int H2 = 64,  W2 = 112;
constexpr int HW0 = H0 * W0;
constexpr int CAP = 8;           // global bin capacity (mean 1/cell)
constexpr int OVCAP = 8192;      // per-level overflow list
constexpr int NC0 = (W0 + 1) * (H0 + 1);   // padded cell grids
constexpr int NC1 = (W1 + 1) * (H1 + 1);
constexpr int NC2 = (W2 + 1) * (H2 + 1);

// np.linspace(-1+1/n, 1-1/n, n, dtype=f32) bit path (backwarp side; validated).
__device__ inline float lin_ac_f32(int i, int n) {
    if (i == n - 1) return (float)(1.0 - 1.0 / (double)n);
    double start = -1.0 + 1.0 / (double)n;
    double step  = (2.0 - 2.0 / (double)n) / (double)(n - 1);
    return (float)(start + (double)i * step);
}

// ---------------------------------------------------------------------------
// Backwarp + L1 occlusion metric, both directions in one launch (validated).
// ---------------------------------------------------------------------------
__global__ __launch_bounds__(256) void metric2_kernel(
        const float* __restrict__ img1, const float* __restrict__ img2,
        const float* __restrict__ fl12, const float* __restrict__ fl21,
        float* __restrict__ m12, float* __restrict__ m21) {
    int idx = blockIdx.x * 256 + threadIdx.x;
    int total = 2 * Bn * HW0;
    if (idx >= total) return;
    int dir = idx / (Bn * HW0);
    int sub = idx % (Bn * HW0);
    const float* imgA = dir ? img2 : img1;
    const float* imgB = dir ? img1 : img2;
    const float* flow = dir ? fl21 : fl12;
    float* mout = dir ? m21 : m12;

    int x = sub % W0;
    int y = (sub / W0) % H0;
    int b = sub / HW0;

    const float* fb = flow + (size_t)b * 2 * HW0;
    float fx = fb[y * W0 + x];
    float fy = fb[(size_t)HW0 + y * W0 + x];

    const float sxc = (float)(2.0 / (double)(W0 - 1));
    const float syc = (float)(2.0 / (double)(H0 - 1));
    float gx = __fadd_rn(lin_ac_f32(x, W0), __fmul_rn(fx, sxc));
    float gy = __fadd_rn(lin_ac_f32(y, H0), __fmul_rn(fy, syc));
    float px = __fmul_rn(__fmul_rn(__fadd_rn(gx, 1.0f), 0.5f), (float)(W0 - 1));
    float py = __fmul_rn(__fmul_rn(__fadd_rn(gy, 1.0f), 0.5f), (float)(H0 - 1));

    float x0f = floorf(px), y0f = floorf(py);
    float x1f = x0f + 1.0f, y1f = y0f + 1.0f;
    int x0 = (int)x0f, y0 = (int)y0f, x1 = (int)x1f, y1 = (int)y1f;

    float tw[4] = { (x1f - px) * (y1f - py), (px - x0f) * (y1f - py),
                    (x1f - px) * (py - y0f), (px - x0f) * (py - y0f) };
    int tx[4] = { x0, x1, x0, x1 };
    int ty[4] = { y0, y0, y1, y1 };

    const float* ib = imgB + (size_t)b * 3 * HW0;
    float acc0 = 0.f, acc1 = 0.f, acc2 = 0.f;
#pragma unroll
    for (int t = 0; t < 4; ++t) {
        bool valid = (tx[t] >= 0) && (tx[t] < W0) && (ty[t] >= 0) && (ty[t] < H0);
        int xc = min(max(tx[t], 0), W0 - 1);
        int yc = min(max(ty[t], 0), H0 - 1);
        float ww = valid ? tw[t] : 0.f;
        int off = yc * W0 + xc;
        acc0 += ib[off] * ww;
        acc1 += ib[(size_t)HW0 + off] * ww;
        acc2 += ib[(size_t)2 * HW0 + off] * ww;
    }
    const float* ia = imgA + (size_t)b * 3 * HW0;
    int off = y * W0 + x;
    float m = (fabsf(ia[off] - acc0) +
               fabsf(ia[(size_t)HW0 + off] - acc1) +
               fabsf(ia[(size_t)2 * HW0 + off] - acc2)) * (1.f / 3.f);
    mout[(size_t)b * HW0 + off] = m;
}

// jax-f32 linspace bit path + endpoint forcing (validated round 6).
__device__ inline void ac32_iota(int i, int n_in, int n_out, float delta,
                                 int& i0, int& i1, float& fr) {
    float v = (i == n_out - 1) ? (float)(n_in - 1) : __fmul_rn(delta, (float)i);
    float f0 = floorf(v);
    i0 = (int)f0;
    i1 = min(i0 + 1, n_in - 1);
    fr = __fsub_rn(v, f0);
}

// Unfused pinned f32 bilinear (validated round 6).
__device__ inline float bilerp32(const float* __restrict__ s, int Win,
                                 int y0, int y1, int x0, int x1,
                                 float wy, float wx) {
    float a = s[y0 * Win + x0], b = s[y1 * Win + x0];
    float c = s[y0 * Win + x1], d = s[y1 * Win + x1];
    float omwy = __fsub_rn(1.0f, wy), omwx = __fsub_rn(1.0f, wx);
    float r0 = __fadd_rn(__fmul_rn(a, omwy), __fmul_rn(b, wy));
    float r1 = __fadd_rn(__fmul_rn(c, omwy), __fmul_rn(d, wy));
    return __fadd_rn(__fmul_rn(r0, omwx), __fmul_rn(r1, wx));
}

// chunked XCD swizzle (grid divisible by 8)
__device__ inline int swz_block(int bid, int nblk) {
    int cpx = nblk >> 3;
    return (bid & 7) * cpx + (bid >> 3);
}

// ---------------------------------------------------------------------------
// Lean geometry: source -> {gx, gy, cell x0/y0} — EXACT round-6 bit paths.
// ---------------------------------------------------------------------------
template<int LVL>
struct Geo {
    float gx, gy;
    int x0, y0;
    int ry0, ry1, rx0, rx1;
    float wy, wx;
};

template<int LVL>
__device__ inline Geo<LVL> geom(int x, int y, int b, int h, int w,
                                const float* __restrict__ flow,
                                float scale, float dly, float dlx) {
    Geo<LVL> g;
    float gx, gy;
    if constexpr (LVL == 0) {
        const float* fb = flow + (size_t)b * 2 * HW0;
        float fx = 0.5f * fb[y * W0 + x];
        float fy = 0.5f * fb[(size_t)HW0 + y * W0 + x];
        gx = (float)x + fx;
        gy = (float)y + fy;
    } else {
        ac32_iota(y, H0, h, dly, g.ry0, g.ry1, g.wy);
        ac32_iota(x, W0, w, dlx, g.rx0, g.rx1, g.wx);
        const float* fB = flow + (size_t)b * 2 * HW0;
        float fx = __fmul_rn(bilerp32(fB, W0, g.ry0, g.ry1, g.rx0, g.rx1, g.wy, g.wx), scale);
        float fy = __fmul_rn(bilerp32(fB + (size_t)HW0, W0, g.ry0, g.ry1, g.rx0, g.rx1, g.wy, g.wx), scale);
        gx = __fadd_rn((float)x, fx);
        gy = __fadd_rn((float)y, fy);
    }
    g.gx = gx; g.gy = gy;
    g.x0 = (int)floorf(gx);
    g.y0 = (int)floorf(gy);
    return g;
}

// Tap weight from stored gx/gy — identical pinned tail (validated R16/R17).
template<int LVL>
__device__ inline float tap_w(float gx, float gy, int t) {
    float x0f = floorf(gx), y0f = floorf(gy);
    if constexpr (LVL == 0) {
        float x1f = x0f + 1.f, y1f = y0f + 1.f;
        return (t == 0) ? (x1f - gx) * (y1f - gy)
             : (t == 1) ? (gx - x0f) * (y1f - gy)
             : (t == 2) ? (x1f - gx) * (gy - y0f)
                        : (gx - x0f) * (gy - y0f);
    } else {
        float x1f = __fadd_rn(x0f, 1.0f), y1f = __fadd_rn(y0f, 1.0f);
        float dx0 = __fsub_rn(x1f, gx), dx1 = __fsub_rn(gx, x0f);
        float dy0 = __fsub_rn(y1f, gy), dy1 = __fsub_rn(gy, y0f);
        return (t == 0) ? __fmul_rn(dx0, dy0)
             : (t == 1) ? __fmul_rn(dx1, dy0)
             : (t == 2) ? __fmul_rn(dx0, dy1)
                        : __fmul_rn(dx1, dy1);
    }
}

// ---------------------------------------------------------------------------
// Global binning: ONE geom+wgt per source (both dirs); entry {gx,gy,wgt,sidx}
// into the padded cell grid (validated R17).
// ---------------------------------------------------------------------------
template<int LVL, int H, int W, int NC>
__global__ __launch_bounds__(256) void bin_kernel(
        const float* __restrict__ fl12, const float* __restrict__ fl21,
        const float* __restrict__ m12, const float* __restrict__ m21,
        const float* __restrict__ alphap,
        int* __restrict__ cnt, float4* __restrict__ ent,
        int* __restrict__ ovn, int* __restrict__ ovkey, float4* __restrict__ ovdata,
        float scale, float dly, float dlx) {
    int idx = blockIdx.x * 256 + threadIdx.x;
    int total = 2 * Bn * H * W;
    if (idx >= total) return;
    int dir = idx / (Bn * H * W);
    int sub = idx % (Bn * H * W);
    const float* flow = dir ? fl21 : fl12;
    const float* met  = dir ? m21 : m12;
    int x = sub % W, y = (sub / W) % H, b = sub / (H * W);

    Geo<LVL> g = geom<LVL>(x, y, b, H, W, flow, scale, dly, dlx);
    if (g.x0 < -1 || g.x0 > W - 1 || g.y0 < -1 || g.y0 > H - 1) return;

    float a = alphap[0];
    float wgt;
    if constexpr (LVL == 0) wgt = expf(a * met[(size_t)b * HW0 + y * W0 + x]);
    else {
        float m = bilerp32(met + (size_t)b * HW0, W0, g.ry0, g.ry1, g.rx0, g.rx1, g.wy, g.wx);
        wgt = expf(__fmul_rn(a, m));
    }

    int cell = (g.y0 + 1) * (W + 1) + (g.x0 + 1);
    int slot = (dir * Bn + b) * NC + cell;
    float4 e;
    e.x = g.gx; e.y = g.gy; e.z = wgt; e.w = __int_as_float(y * W + x);
    int pos = atomicAdd(&cnt[slot], 1);
    if (pos < CAP) ent[(size_t)slot * CAP + pos] = e;
    else {
        int p2 = atomicAdd(ovn, 1);
        if (p2 < OVCAP) { ovkey[p2] = slot; ovdata[p2] = e; }
    }
}

// ---------------------------------------------------------------------------
// NCHW -> NHWC transpose (values only; validated, unchanged).
// ---------------------------------------------------------------------------
template<int CH>
__global__ __launch_bounds__(256) void transpose_kernel(const float* __restrict__ src0, int C0,
                                                        const float* __restrict__ src1, int C1,
                                                        float* __restrict__ dst, int HW) {
    __shared__ float lds[128 * CH];
    int gp = blockIdx.x * 128;
    int b = gp / HW, p0 = gp % HW;
    int tid = threadIdx.x;
    int CT = C0 + C1;
    for (int i = tid; i < 128 * CH; i += 256) {
        int c = i / 128, p = i % 128;
        float v = 0.f;
        if (c < C0) v = src0[((size_t)b * C0 + c) * HW + p0 + p];
        else if (c < CT) v = src1[((size_t)b * C1 + (c - C0)) * HW + p0 + p];
        lds[p * CH + c] = v;
    }
    __syncthreads();
    float4* d4 = (float4*)(dst + (size_t)gp * CH);
    const int N4 = 128 * CH / 4;
    for (int i = tid; i < N4; i += 256) {
        int base = i * 4;
        float4 q = { lds[base], lds[base + 1], lds[base + 2], lds[base + 3] };
        d4[i] = q;
    }
}

// ---------------------------------------------------------------------------
// Gather (hybrid): tile block COOPERATIVELY STAGES its 17x17 cell bins from
// the global bin structure into LDS (one thread per cell, each read once),
// then runs the validated R16 LDS-bin register gather. No scans, no per-pixel
// scattered global bin reads. Overflow merged per-thread (expected 0).
// ---------------------------------------------------------------------------
template<int LVL, int CREAL, int CBT4, int NV0, int NV1, int H, int W, int NC>
__global__ __launch_bounds__(512) void gather_kernel(
        const float4* __restrict__ nhwc,
        const int* __restrict__ cnt, const float4* __restrict__ ent,
        const int* __restrict__ ovn_p, const int* __restrict__ ovkey,
        const float4* __restrict__ ovdata,
        float* __restrict__ outp, int Cout, int cbase, int dir) {
    constexpr int TW = 16, TH = 16;
    constexpr int NBX = TW + 1, NB = NBX * (TH + 1);   // 289 cells
    constexpr int NVM = (NV0 > NV1) ? NV0 : NV1;
    constexpr int HW_ = H * W;
    __shared__ int   bcnt[NB];
    __shared__ int   bsidx[NB * CAP];
    __shared__ float bgx[NB * CAP], bgy[NB * CAP], bwgt[NB * CAP];

    const int tilesX = W / TW, tilesY = H / TH;
    int s = swz_block(blockIdx.x, gridDim.x);
    int tpb = tilesX * tilesY;
    int b = s / tpb, r = s % tpb;
    int ty0 = (r / tilesX) * TH, tx0 = (r % tilesX) * TW;
    int tid = threadIdx.x;
    int base = (dir * Bn + b) * NC;

    // ---- stage: one thread per cell ----
    for (int i = tid; i < NB; i += 512) {
        int cx = tx0 - 1 + i % NBX;
        int cy = ty0 - 1 + i / NBX;
        int slot = base + (cy + 1) * (W + 1) + (cx + 1);
        int n = min(cnt[slot], CAP);
        bcnt[i] = n;
        for (int j = 0; j < n; ++j) {
            float4 e = ent[(size_t)slot * CAP + j];
            bsidx[i * CAP + j] = __float_as_int(e.w);
            bgx[i * CAP + j] = e.x;
            bgy[i * CAP + j] = e.y;
            bwgt[i * CAP + j] = e.z;
        }
    }
    __syncthreads();

    // ---- per (pixel, half) register gather (validated R16 phase 2) ----
    int pixel = tid & 255, half = tid >> 8;
    int px = tx0 + (pixel & 15), py = ty0 + (pixel >> 4);
    int voff = half ? NV0 : 0;
    int nv = half ? NV1 : NV0;
    const float4* nbp = nhwc + (size_t)b * HW_ * CBT4 + voff;
    float ax[NVM], ay[NVM], az[NVM], aw[NVM];
#pragma unroll
    for (int vi = 0; vi < NVM; ++vi) { ax[vi] = 0.f; ay[vi] = 0.f; az[vi] = 0.f; aw[vi] = 0.f; }
    float wacc = 0.f;

#pragma unroll
    for (int cyi = 0; cyi < 2; ++cyi)
#pragma unroll
    for (int cxi = 0; cxi < 2; ++cxi) {
        const int t = (1 - cyi) * 2 + (1 - cxi);
        int lc = (py - ty0 + cyi) * NBX + (px - tx0 + cxi);
        int n = bcnt[lc];
        for (int j = 0; j < n; ++j) {
            int e = lc * CAP + j;
            float tw = tap_w<LVL>(bgx[e], bgy[e], t);
            float wgt = bwgt[e];
            const float4* vp = nbp + (size_t)bsidx[e] * CBT4;
            if constexpr (LVL == 0) {
                float twv = tw * wgt;
                wacc += twv;
#pragma unroll
                for (int vi = 0; vi < NVM; ++vi) {
                    if (vi >= nv) break;
                    float4 q = vp[vi];
                    ax[vi] += q.x * twv; ay[vi] += q.y * twv;
                    az[vi] += q.z * twv; aw[vi] += q.w * twv;
                }
            } else {
                wacc += __fmul_rn(wgt, tw);
#pragma unroll
                for (int vi = 0; vi < NVM; ++vi) {
                    if (vi >= nv) break;
                    float4 q = vp[vi];
                    ax[vi] += __fmul_rn(__fmul_rn(q.x, wgt), tw);
                    ay[vi] += __fmul_rn(__fmul_rn(q.y, wgt), tw);
                    az[vi] += __fmul_rn(__fmul_rn(q.z, wgt), tw);
                    aw[vi] += __fmul_rn(__fmul_rn(q.w, wgt), tw);
                }
            }
        }
    }

    // overflow entries (expected ~0 at CAP=8)
    int novr = min(ovn_p[0], OVCAP);
    for (int j = 0; j < novr; ++j) {
        int key = ovkey[j];
        int t = -1;
#pragma unroll
        for (int cyi = 0; cyi < 2; ++cyi)
#pragma unroll
        for (int cxi = 0; cxi < 2; ++cxi) {
            int slot = base + (py - 1 + cyi + 1) * (W + 1) + (px - 1 + cxi + 1);
            if (key == slot) t = (1 - cyi) * 2 + (1 - cxi);
        }
        if (t < 0) continue;
        float4 e = ovdata[j];
        float tw = tap_w<LVL>(e.x, e.y, t);
        float wgt = e.z;
        const float4* vp = nbp + (size_t)__float_as_int(e.w) * CBT4;
        if constexpr (LVL == 0) {
            float twv = tw * wgt;
            wacc += twv;
#pragma unroll
            for (int vi = 0; vi < NVM; ++vi) {
                if (vi >= nv) break;
                float4 q = vp[vi];
                ax[vi] += q.x * twv; ay[vi] += q.y * twv;
                az[vi] += q.z * twv; aw[vi] += q.w * twv;
            }
        } else {
            wacc += __fmul_rn(wgt, tw);
#pragma unroll
            for (int vi = 0; vi < NVM; ++vi) {
                if (vi >= nv) break;
                float4 q = vp[vi];
                ax[vi] += __fmul_rn(__fmul_rn(q.x, wgt), tw);
                ay[vi] += __fmul_rn(__fmul_rn(q.y, wgt), tw);
                az[vi] += __fmul_rn(__fmul_rn(q.z, wgt), tw);
                aw[vi] += __fmul_rn(__fmul_rn(q.w, wgt), tw);
            }
        }
    }

    float denom = wacc + 1e-7f;
    size_t obase = ((size_t)b * Cout + cbase) * HW_ + (py * W + px);
#pragma unroll
    for (int vi = 0; vi < NVM; ++vi) {
        if (vi >= nv) break;
        int c0 = (voff + vi) * 4;
        if (c0 + 0 < CREAL) outp[obase + (size_t)(c0 + 0) * HW_] = ax[vi] / denom;
        if (c0 + 1 < CREAL) outp[obase + (size_t)(c0 + 1) * HW_] = ay[vi] / denom;
        if (c0 + 2 < CREAL) outp[obase + (size_t)(c0 + 2) * HW_] = az[vi] / denom;
        if (c0 + 3 < CREAL) outp[obase + (size_t)(c0 + 3) * HW_] = aw[vi] / denom;
    }
}

inline int nblk(long long n) { return (int)((n + 255) / 256); }

} // namespace

extern "C" void kernel_launch(void* const* d_in, const int* in_sizes, int n_in,
                              void* d_out, int out_size, void* d_ws, size_t ws_size,
                              hipStream_t stream) {
    const float* img1 = (const float*)d_in[0];
    const float* img2 = (const float*)d_in[1];
    const float* f1_1 = (const float*)d_in[2];
    const float* f1_2 = (const float*)d_in[3];
    const float* f1_3 = (const float*)d_in[4];
    const float* f2_1 = (const float*)d_in[5];
    const float* f2_2 = (const float*)d_in[6];
    const float* f2_3 = (const float*)d_in[7];
    const float* fl12 = (const float*)d_in[8];
    const float* fl21 = (const float*)d_in[9];
    const float* alpha = (const float*)d_in[10];
    float* out = (float*)d_out;

    const float dy1 = (float)(H0 - 1) / (float)(H1 - 1);
    const float dx1 = (float)(W0 - 1) / (float)(W1 - 1);
    const float dy2 = (float)(H0 - 1) / (float)(H2 - 1);
    const float dx2 = (float)(W0 - 1) / (float)(W2 - 1);

    // ---- workspace layout (float4 arrays first for alignment) ----
    float4* entL0  = (float4*)d_ws;                        // 8*NC0*CAP
    float4* entL1  = entL0 + (size_t)8 * NC0 * CAP;
    float4* entL2  = entL1 + (size_t)8 * NC1 * CAP;
    float4* ovdata = entL2 + (size_t)8 * NC2 * CAP;        // 3*OVCAP
    float*  nhwcW  = (float*)(ovdata + 3 * OVCAP);         // L1/L2 NHWC reuse
    float*  m12    = nhwcW + (size_t)Bn * H1 * W1 * 64;
    float*  m21    = m12 + (size_t)Bn * HW0;
    int*    cnt0   = (int*)(m21 + (size_t)Bn * HW0);       // 8*NC0
    int*    cnt1   = cnt0 + (size_t)8 * NC0;
    int*    cnt2   = cnt1 + (size_t)8 * NC1;
    int*    ovn    = cnt2 + (size_t)8 * NC2;               // 16 ints
    int*    ovkey  = ovn + 16;                             // 3*OVCAP ints
    size_t zero_bytes = ((size_t)8 * (NC0 + NC1 + NC2) + 16) * sizeof(int);

    float* l1 = out;
    float* l2 = l1 + (size_t)Bn * 70 * HW0;
    float* nhwc0 = l2;                                     // L0 NHWC in unwritten l2+l3
    float* l3 = l2 + (size_t)Bn * 128 * (H1 * W1);

    (void)hipMemsetAsync(cnt0, 0, zero_bytes, stream);

    metric2_kernel<<<nblk((long long)2 * Bn * HW0), 256, 0, stream>>>(
        img1, img2, fl12, fl21, m12, m21);

    bin_kernel<0, H0, W0, NC0><<<2 * Bn * HW0 / 256, 256, 0, stream>>>(
        fl12, fl21, m12, m21, alpha, cnt0, entL0, ovn + 0, ovkey, ovdata, 0.f, 0.f, 0.f);
    bin_kernel<1, H1, W1, NC1><<<2 * Bn * H1 * W1 / 256, 256, 0, stream>>>(
        fl12, fl21, m12, m21, alpha, cnt1, entL1, ovn + 1, ovkey + OVCAP, ovdata + OVCAP,
        0.25f, dy1, dx1);
    bin_kernel<1, H2, W2, NC2><<<2 * Bn * H2 * W2 / 256, 256, 0, stream>>>(
        fl12, fl21, m12, m21, alpha, cnt2, entL2, ovn + 2, ovkey + 2 * OVCAP, ovdata + 2 * OVCAP,
        0.125f, dy2, dx2);

    const int GT0 = Bn * HW0 / 128, GT1 = Bn * H1 * W1 / 128, GT2 = Bn * H2 * W2 / 128;
    const int GG0 = Bn * (H0 / 16) * (W0 / 16);   // 1792
    const int GG1 = Bn * (H1 / 16) * (W1 / 16);   // 448
    const int GG2 = Bn * (H2 / 16) * (W2 / 16);   // 112

    // ================= level 0 =================
    transpose_kernel<36><<<GT0, 256, 0, stream>>>(img1, 3, f1_1, 32, nhwc0, HW0);
    gather_kernel<0, 35, 9, 5, 4, H0, W0, NC0><<<GG0, 512, 0, stream>>>(
        (const float4*)nhwc0, cnt0, entL0, ovn + 0, ovkey, ovdata, l1, 70, 0, 0);
    transpose_kernel<36><<<GT0, 256, 0, stream>>>(img2, 3, f2_1, 32, nhwc0, HW0);
    gather_kernel<0, 35, 9, 5, 4, H0, W0, NC0><<<GG0, 512, 0, stream>>>(
        (const float4*)nhwc0, cnt0, entL0, ovn + 0, ovkey, ovdata, l1, 70, 35, 1);

    // ================= level 1 =================
    transpose_kernel<64><<<GT1, 256, 0, stream>>>(f1_2, 64, nullptr, 0, nhwcW, H1 * W1);
    gather_kernel<1, 64, 16, 8, 8, H1, W1, NC1><<<GG1, 512, 0, stream>>>(
        (const float4*)nhwcW, cnt1, entL1, ovn + 1, ovkey + OVCAP, ovdata + OVCAP,
        l2, 128, 0, 0);
    transpose_kernel<64><<<GT1, 256, 0, stream>>>(f2_2, 64, nullptr, 0, nhwcW, H1 * W1);
    gather_kernel<1, 64, 16, 8, 8, H1, W1, NC1><<<GG1, 512, 0, stream>>>(
        (const float4*)nhwcW, cnt1, entL1, ovn + 1, ovkey + OVCAP, ovdata + OVCAP,
        l2, 128, 64, 1);

    // ================= level 2 =================
    transpose_kernel<96><<<GT2, 256, 0, stream>>>(f1_3, 96, nullptr, 0, nhwcW, H2 * W2);
    gather_kernel<1, 96, 24, 12, 12, H2, W2, NC2><<<GG2, 512, 0, stream>>>(
        (const float4*)nhwcW, cnt2, entL2, ovn + 2, ovkey + 2 * OVCAP, ovdata + 2 * OVCAP,
        l3, 192, 0, 0);
    transpose_kernel<96><<<GT2, 256, 0, stream>>>(f2_3, 96, nullptr, 0, nhwcW, H2 * W2);
    gather_kernel<1, 96, 24, 12, 12, H2, W2, NC2><<<GG2, 512, 0, stream>>>(
        (const float4*)nhwcW, cnt2, entL2, ovn + 2, ovkey + 2 * OVCAP, ovdata + 2 * OVCAP,
        l3, 192, 96, 1);
}

// Round 19
// 514.925 us; speedup vs baseline: 1.1537x; 1.0796x over previous
//
#include <hip/hip_runtime.h>
#include <math.h>

namespace {

constexpr int Bn = 4;
constexpr int H0 = 256, W0 = 448;
constexpr int H1 = 128, W1 = 224;
constexpr int H2 = 64,  W2 = 112;
constexpr int HW0 = H0 * W0;
constexpr int HW1 = H1 * W1;
constexpr int HW2 = H2 * W2;
constexpr int IRRCAP = 8192;
constexpr int OVCAP  = 4096;
constexpr int KB = 10;     // LDS bin capacity (validated R16)

// np.linspace(-1+1/n, 1-1/n, n, dtype=f32) bit path (backwarp side; validated).
__device__ inline float lin_ac_f32(int i, int n) {
    if (i == n - 1) return (float)(1.0 - 1.0 / (double)n);
    double start = -1.0 + 1.0 / (double)n;
    double step  = (2.0 - 2.0 / (double)n) / (double)(n - 1);
    return (float)(start + (double)i * step);
}

// jax-f32 linspace bit path + endpoint forcing (validated round 6).
__device__ inline void ac32_iota(int i, int n_in, int n_out, float delta,
                                 int& i0, int& i1, float& fr) {
    float v = (i == n_out - 1) ? (float)(n_in - 1) : __fmul_rn(delta, (float)i);
    float f0 = floorf(v);
    i0 = (int)f0;
    i1 = min(i0 + 1, n_in - 1);
    fr = __fsub_rn(v, f0);
}

// Unfused pinned f32 bilinear (validated round 6).
__device__ inline float bilerp32(const float* __restrict__ s, int Win,
                                 int y0, int y1, int x0, int x1,
                                 float wy, float wx) {
    float a = s[y0 * Win + x0], b = s[y1 * Win + x0];
    float c = s[y0 * Win + x1], d = s[y1 * Win + x1];
    float omwy = __fsub_rn(1.0f, wy), omwx = __fsub_rn(1.0f, wx);
    float r0 = __fadd_rn(__fmul_rn(a, omwy), __fmul_rn(b, wy));
    float r1 = __fadd_rn(__fmul_rn(c, omwy), __fmul_rn(d, wy));
    return __fadd_rn(__fmul_rn(r0, omwx), __fmul_rn(r1, wx));
}

// chunked XCD swizzle (grid divisible by 8)
__device__ inline int swz_block(int bid, int nblk) {
    int cpx = nblk >> 3;
    return (bid & 7) * cpx + (bid >> 3);
}

// ---------------------------------------------------------------------------
// Tap geometry — EXACT round-6/R16 bit paths (validated).
// ---------------------------------------------------------------------------
template<int LVL, int D>
struct Geo {
    int   tx[4], ty[4];
    float tw[4];
    float gx, gy;
    bool  reg;
    int   ry0, ry1, rx0, rx1;
    float wy, wx;
};

template<int LVL, int D>
__device__ inline Geo<LVL, D> geom(int x, int y, int b, int h, int w,
                                   const float* __restrict__ flow,
                                   float scale, float dly, float dlx) {
    Geo<LVL, D> g;
    float gx, gy, x0f, y0f, x1f, y1f;
    if constexpr (LVL == 0) {
        const float* fb = flow + (size_t)b * 2 * HW0;
        float fx = 0.5f * fb[y * W0 + x];
        float fy = 0.5f * fb[(size_t)HW0 + y * W0 + x];
        gx = (float)x + fx;
        gy = (float)y + fy;
        x0f = floorf(gx); y0f = floorf(gy);
        x1f = x0f + 1.f;  y1f = y0f + 1.f;
        g.tw[0] = (x1f - gx) * (y1f - gy); g.tw[1] = (gx - x0f) * (y1f - gy);
        g.tw[2] = (x1f - gx) * (gy - y0f); g.tw[3] = (gx - x0f) * (gy - y0f);
    } else {
        ac32_iota(y, H0, h, dly, g.ry0, g.ry1, g.wy);
        ac32_iota(x, W0, w, dlx, g.rx0, g.rx1, g.wx);
        const float* fB = flow + (size_t)b * 2 * HW0;
        float fx = __fmul_rn(bilerp32(fB, W0, g.ry0, g.ry1, g.rx0, g.rx1, g.wy, g.wx), scale);
        float fy = __fmul_rn(bilerp32(fB + (size_t)HW0, W0, g.ry0, g.ry1, g.rx0, g.rx1, g.wy, g.wx), scale);
        gx = __fadd_rn((float)x, fx);
        gy = __fadd_rn((float)y, fy);
        x0f = floorf(gx); y0f = floorf(gy);
        x1f = __fadd_rn(x0f, 1.0f); y1f = __fadd_rn(y0f, 1.0f);
        float dx0 = __fsub_rn(x1f, gx), dx1 = __fsub_rn(gx, x0f);
        float dy0 = __fsub_rn(y1f, gy), dy1 = __fsub_rn(gy, y0f);
        g.tw[0] = __fmul_rn(dx0, dy0); g.tw[1] = __fmul_rn(dx1, dy0);
        g.tw[2] = __fmul_rn(dx0, dy1); g.tw[3] = __fmul_rn(dx1, dy1);
    }
    g.gx = gx; g.gy = gy;
    int x0 = (int)x0f, y0 = (int)y0f;
    g.tx[0] = x0;     g.tx[1] = x0 + 1; g.tx[2] = x0;     g.tx[3] = x0 + 1;
    g.ty[0] = y0;     g.ty[1] = y0;     g.ty[2] = y0 + 1; g.ty[3] = y0 + 1;
    g.reg = (x0 >= x - D) && (x0 + 1 <= x + D) && (y0 >= y - D) && (y0 + 1 <= y + D);
    return g;
}

// ---------------------------------------------------------------------------
// Metric (both dirs) FUSED with L0 irregular detection.
// Metric bit path validated; L0 irr predicate identical to R16 irr_kernel.
// irr entry pack: (dir<<20)|(b<<18)|sidx  (sidx < 2^17).
// ---------------------------------------------------------------------------
__global__ __launch_bounds__(256) void metric2irr0_kernel(
        const float* __restrict__ img1, const float* __restrict__ img2,
        const float* __restrict__ fl12, const float* __restrict__ fl21,
        float* __restrict__ m12, float* __restrict__ m21,
        int* __restrict__ irrcnt, int* __restrict__ irrlist) {
    int idx = blockIdx.x * 256 + threadIdx.x;
    int total = 2 * Bn * HW0;
    if (idx >= total) return;
    int dir = idx / (Bn * HW0);
    int sub = idx % (Bn * HW0);
    const float* imgA = dir ? img2 : img1;
    const float* imgB = dir ? img1 : img2;
    const float* flow = dir ? fl21 : fl12;
    float* mout = dir ? m21 : m12;

    int x = sub % W0;
    int y = (sub / W0) % H0;
    int b = sub / HW0;

    const float* fb = flow + (size_t)b * 2 * HW0;
    float fx = fb[y * W0 + x];
    float fy = fb[(size_t)HW0 + y * W0 + x];

    // ---- metric (validated bit path) ----
    const float sxc = (float)(2.0 / (double)(W0 - 1));
    const float syc = (float)(2.0 / (double)(H0 - 1));
    float ggx = __fadd_rn(lin_ac_f32(x, W0), __fmul_rn(fx, sxc));
    float ggy = __fadd_rn(lin_ac_f32(y, H0), __fmul_rn(fy, syc));
    float px = __fmul_rn(__fmul_rn(__fadd_rn(ggx, 1.0f), 0.5f), (float)(W0 - 1));
    float py = __fmul_rn(__fmul_rn(__fadd_rn(ggy, 1.0f), 0.5f), (float)(H0 - 1));

    float x0f = floorf(px), y0f = floorf(py);
    float x1f = x0f + 1.0f, y1f = y0f + 1.0f;
    int x0 = (int)x0f, y0 = (int)y0f, x1 = (int)x1f, y1 = (int)y1f;

    float tw[4] = { (x1f - px) * (y1f - py), (px - x0f) * (y1f - py),
                    (x1f - px) * (py - y0f), (px - x0f) * (py - y0f) };
    int tx[4] = { x0, x1, x0, x1 };
    int ty[4] = { y0, y0, y1, y1 };

    const float* ib = imgB + (size_t)b * 3 * HW0;
    float acc0 = 0.f, acc1 = 0.f, acc2 = 0.f;
#pragma unroll
    for (int t = 0; t < 4; ++t) {
        bool valid = (tx[t] >= 0) && (tx[t] < W0) && (ty[t] >= 0) && (ty[t] < H0);
        int xc = min(max(tx[t], 0), W0 - 1);
        int yc = min(max(ty[t], 0), H0 - 1);
        float ww = valid ? tw[t] : 0.f;
        int off = yc * W0 + xc;
        acc0 += ib[off] * ww;
        acc1 += ib[(size_t)HW0 + off] * ww;
        acc2 += ib[(size_t)2 * HW0 + off] * ww;
    }
    const float* ia = imgA + (size_t)b * 3 * HW0;
    int off = y * W0 + x;
    float m = (fabsf(ia[off] - acc0) +
               fabsf(ia[(size_t)HW0 + off] - acc1) +
               fabsf(ia[(size_t)2 * HW0 + off] - acc2)) * (1.f / 3.f);
    mout[(size_t)b * HW0 + off] = m;

    // ---- L0 irregular detection (identical predicate to R16 irr<0,16>) ----
    float fxh = 0.5f * fx;
    float fyh = 0.5f * fy;
    float sgx = (float)x + fxh;
    float sgy = (float)y + fyh;
    int sx0 = (int)floorf(sgx);
    int sy0 = (int)floorf(sgy);
    bool reg = (sx0 >= x - 16) && (sx0 + 1 <= x + 16) &&
               (sy0 >= y - 16) && (sy0 + 1 <= y + 16);
    if (reg) return;
    bool any = (sx0 >= -1) && (sx0 <= W0 - 1) && (sy0 >= -1) && (sy0 <= H0 - 1);
    if (!any) return;
    int pos = atomicAdd(irrcnt, 1);
    if (pos < IRRCAP) irrlist[pos] = (dir << 20) | (b << 18) | (y * W0 + x);
}

// ---------------------------------------------------------------------------
// Irregular detection for L1+L2 (one launch, segmented; both dirs).
// ---------------------------------------------------------------------------
__global__ __launch_bounds__(256) void irr12_kernel(
        const float* __restrict__ fl12, const float* __restrict__ fl21,
        int* __restrict__ irrcnt1, int* __restrict__ irrlist1,
        int* __restrict__ irrcnt2, int* __restrict__ irrlist2,
        float dy1v, float dx1v, float dy2v, float dx2v) {
    int idx = blockIdx.x * 256 + threadIdx.x;
    const int n1 = 2 * Bn * HW1;
    const int n2 = 2 * Bn * HW2;
    if (idx >= n1 + n2) return;
    int lvl2 = (idx >= n1);
    int sub2 = lvl2 ? (idx - n1) : idx;
    int h = lvl2 ? H2 : H1, w = lvl2 ? W2 : W1;
    float scale = lvl2 ? 0.125f : 0.25f;
    float dly = lvl2 ? dy2v : dy1v, dlx = lvl2 ? dx2v : dx1v;
    int* cnt = lvl2 ? irrcnt2 : irrcnt1;
    int* list = lvl2 ? irrlist2 : irrlist1;

    int hw = h * w;
    int dir = sub2 / (Bn * hw);
    int sub = sub2 % (Bn * hw);
    const float* flow = dir ? fl21 : fl12;
    int x = sub % w, y = (sub / w) % h, b = sub / hw;

    Geo<1, 8> g = geom<1, 8>(x, y, b, h, w, flow, scale, dly, dlx);
    if (g.reg) return;
    bool any = false;
#pragma unroll
    for (int t = 0; t < 4; ++t)
        any = any || ((g.tx[t] >= 0) && (g.tx[t] < w) && (g.ty[t] >= 0) && (g.ty[t] < h));
    if (!any) return;
    int pos = atomicAdd(cnt, 1);
    if (pos < IRRCAP) list[pos] = (dir << 20) | (b << 18) | (y * w + x);
}

// ---------------------------------------------------------------------------
// All 6 NCHW -> NHWC transposes in one launch (runtime CH; validated body).
// ---------------------------------------------------------------------------
struct TSegs {
    const float* s0[6];
    const float* s1[6];
    float*       d[6];
    int C0[6], C1[6], CH[6], HW[6];
    int start[7];
};

__global__ __launch_bounds__(256) void transpose_all_kernel(TSegs ts) {
    __shared__ float lds[128 * 96];
    int bid = blockIdx.x;
    int k = 0;
#pragma unroll
    for (int i = 1; i < 6; ++i) if (bid >= ts.start[i]) k = i;
    int HW = ts.HW[k], CH = ts.CH[k], C0 = ts.C0[k], C1 = ts.C1[k];
    const float* s0 = ts.s0[k];
    const float* s1 = ts.s1[k];
    float* dst = ts.d[k];
    int gp = (bid - ts.start[k]) * 128;
    int b = gp / HW, p0 = gp % HW;
    int tid = threadIdx.x;
    int CT = C0 + C1;
    for (int i = tid; i < 128 * CH; i += 256) {
        int c = i / 128, p = i % 128;
        float v = 0.f;
        if (c < C0) v = s0[((size_t)b * C0 + c) * HW + p0 + p];
        else if (c < CT) v = s1[((size_t)b * C1 + (c - C0)) * HW + p0 + p];
        lds[p * CH + c] = v;
    }
    __syncthreads();
    float4* d4 = (float4*)(dst + (size_t)gp * CH);
    int N4 = 128 * CH / 4;
    for (int i = tid; i < N4; i += 256) {
        int base = i * 4;
        float4 q = { lds[base], lds[base + 1], lds[base + 2], lds[base + 3] };
        d4[i] = q;
    }
}

// ---------------------------------------------------------------------------
// Full-recompute gather (overflow path only; rare). Validated R16 body.
// ---------------------------------------------------------------------------
template<int LVL, int D, int H, int W, int CBT4, int NVM>
__device__ inline void gather_one(int sidx, int b, int px, int py, int voff, int nv,
        const float* __restrict__ flow, const float* __restrict__ met, float a,
        float scale, float dly, float dlx, const float4* __restrict__ nhwc,
        float (&ax)[NVM], float (&ay)[NVM], float (&az)[NVM], float (&aw)[NVM],
        float& wacc) {
    int sx = sidx % W, sy = sidx / W;
    Geo<LVL, D> g = geom<LVL, D>(sx, sy, b, H, W, flow, scale, dly, dlx);
    int ddx = px - g.tx[0], ddy = py - g.ty[0];
    if (((unsigned)ddx > 1u) || ((unsigned)ddy > 1u)) return;
    int t = ddy * 2 + ddx;
    float wgt;
    if constexpr (LVL == 0) wgt = expf(a * met[(size_t)b * HW0 + sy * W0 + sx]);
    else {
        float m = bilerp32(met + (size_t)b * HW0, W0, g.ry0, g.ry1, g.rx0, g.rx1, g.wy, g.wx);
        wgt = expf(__fmul_rn(a, m));
    }
    float tw = (t == 0) ? g.tw[0] : (t == 1) ? g.tw[1] : (t == 2) ? g.tw[2] : g.tw[3];
    float twv = (LVL == 0) ? tw * wgt : __fmul_rn(wgt, tw);
    wacc += twv;
    const float4* vp = nhwc + ((size_t)b * (H * W) + sidx) * CBT4 + voff;
#pragma unroll
    for (int vi = 0; vi < NVM; ++vi) {
        if (vi >= nv) break;
        float4 q = vp[vi];
        if constexpr (LVL == 0) {
            ax[vi] += q.x * twv; ay[vi] += q.y * twv;
            az[vi] += q.z * twv; aw[vi] += q.w * twv;
        } else {
            ax[vi] += __fmul_rn(__fmul_rn(q.x, wgt), tw);
            ay[vi] += __fmul_rn(__fmul_rn(q.y, wgt), tw);
            az[vi] += __fmul_rn(__fmul_rn(q.z, wgt), tw);
            aw[vi] += __fmul_rn(__fmul_rn(q.w, wgt), tw);
        }
    }
}

// ---------------------------------------------------------------------------
// Gather: R16's validated scan+LDS-bin structure, both dirs in one launch
// (dir decoded from block id; per-block work byte-identical to R16).
// ---------------------------------------------------------------------------
template<int LVL, int CREAL, int CBT4, int NV0, int NV1, int D, int H, int W>
__global__ __launch_bounds__(512) void gather_kernel(
        const float4* __restrict__ nhwcA, const float4* __restrict__ nhwcB,
        const float* __restrict__ fl12, const float* __restrict__ fl21,
        const float* __restrict__ m12, const float* __restrict__ m21,
        const float* __restrict__ alphap,
        const int* __restrict__ irrn_p, const int* __restrict__ irrlist,
        int* __restrict__ ovn_p, int* __restrict__ ovlist,
        float* __restrict__ outp, int Cout, int cbase0, int cbase1,
        float scale, float dly, float dlx) {
    constexpr int TW = 16, TH = 16;
    constexpr int NBX = TW + 1, NB = NBX * (TH + 1);
    constexpr int NVM = (NV0 > NV1) ? NV0 : NV1;
    constexpr int HW_ = H * W;
    __shared__ int   bcnt[NB];
    __shared__ int   bsidx[NB * KB];
    __shared__ float bgx[NB * KB], bgy[NB * KB], bwgt[NB * KB];
    __shared__ int s_irrn, s_ovn;

    const int tilesX = W / TW, tilesY = H / TH;
    int s = swz_block(blockIdx.x, gridDim.x);
    int tpb = tilesX * tilesY;
    int dir = s / (Bn * tpb);
    int rem = s % (Bn * tpb);
    int b = rem / tpb, r = rem % tpb;
    int ty0 = (r / tilesX) * TH, tx0 = (r % tilesX) * TW;
    int tid = threadIdx.x;

    const float* flow = dir ? fl21 : fl12;
    const float* met  = dir ? m21 : m12;
    const float4* nhwc = dir ? nhwcB : nhwcA;
    int cbase = dir ? cbase1 : cbase0;

    for (int i = tid; i < NB; i += 512) bcnt[i] = 0;
    if (tid == 0) s_irrn = irrn_p[0];
    __syncthreads();

    float a = alphap[0];

    // ---- phase 1a: window scan; bin {sidx,gx,gy,wgt} by destination cell --
    constexpr int WH = TH + 2 * D, WW2 = TW + 2 * D;
    int wy0 = ty0 - D, wx0 = tx0 - D;
    for (int i = tid; i < WH * WW2; i += 512) {
        int sy = wy0 + i / WW2, sx = wx0 + i % WW2;
        if (sy < 0 || sy >= H || sx < 0 || sx >= W) continue;
        Geo<LVL, D> g = geom<LVL, D>(sx, sy, b, H, W, flow, scale, dly, dlx);
        if (!g.reg) continue;
        int cx = g.tx[0], cy = g.ty[0];
        if (cx < tx0 - 1 || cx > tx0 + TW - 1 || cy < ty0 - 1 || cy > ty0 + TH - 1) continue;
        float wgt;
        if constexpr (LVL == 0) wgt = expf(a * met[(size_t)b * HW0 + sy * W0 + sx]);
        else {
            float m = bilerp32(met + (size_t)b * HW0, W0, g.ry0, g.ry1, g.rx0, g.rx1, g.wy, g.wx);
            wgt = expf(__fmul_rn(a, m));
        }
        int bin = (cy - (ty0 - 1)) * NBX + (cx - (tx0 - 1));
        int pos = atomicAdd(&bcnt[bin], 1);
        int sidx = sy * W + sx;
        if (pos < KB) {
            int e = bin * KB + pos;
            bsidx[e] = sidx; bgx[e] = g.gx; bgy[e] = g.gy; bwgt[e] = wgt;
        } else {
            int p2 = atomicAdd(ovn_p, 1);
            if (p2 < OVCAP) { atomicExch(&ovlist[2 * p2], s); atomicExch(&ovlist[2 * p2 + 1], sidx); }
        }
    }
    // ---- phase 1b: bin irregular sources (dir+batch filtered) ----
    int ni = min(s_irrn, IRRCAP);
    for (int i = tid; i < ni; i += 512) {
        int e0 = irrlist[i];
        if ((e0 >> 20) != dir) continue;
        if (((e0 >> 18) & 3) != b) continue;
        int sidx = e0 & ((1 << 18) - 1);
        int sx = sidx % W, sy = sidx / W;
        Geo<LVL, D> g = geom<LVL, D>(sx, sy, b, H, W, flow, scale, dly, dlx);
        int cx = g.tx[0], cy = g.ty[0];
        if (cx < tx0 - 1 || cx > tx0 + TW - 1 || cy < ty0 - 1 || cy > ty0 + TH - 1) continue;
        float wgt;
        if constexpr (LVL == 0) wgt = expf(a * met[(size_t)b * HW0 + sy * W0 + sx]);
        else {
            float m = bilerp32(met + (size_t)b * HW0, W0, g.ry0, g.ry1, g.rx0, g.rx1, g.wy, g.wx);
            wgt = expf(__fmul_rn(a, m));
        }
        int bin = (cy - (ty0 - 1)) * NBX + (cx - (tx0 - 1));
        int pos = atomicAdd(&bcnt[bin], 1);
        if (pos < KB) {
            int e = bin * KB + pos;
            bsidx[e] = sidx; bgx[e] = g.gx; bgy[e] = g.gy; bwgt[e] = wgt;
        } else {
            int p2 = atomicAdd(ovn_p, 1);
            if (p2 < OVCAP) { atomicExch(&ovlist[2 * p2], s); atomicExch(&ovlist[2 * p2 + 1], sidx); }
        }
    }
    __syncthreads();
    if (tid == 0) s_ovn = atomicAdd(ovn_p, 0);
    __syncthreads();

    // ---- phase 2: per (pixel, half) register gather (validated) ----
    int pixel = tid & 255, half = tid >> 8;
    int px = tx0 + (pixel & 15), py = ty0 + (pixel >> 4);
    int voff = half ? NV0 : 0;
    int nv = half ? NV1 : NV0;
    const float4* nbp = nhwc + (size_t)b * HW_ * CBT4 + voff;
    float ax[NVM], ay[NVM], az[NVM], aw[NVM];
#pragma unroll
    for (int vi = 0; vi < NVM; ++vi) { ax[vi] = 0.f; ay[vi] = 0.f; az[vi] = 0.f; aw[vi] = 0.f; }
    float wacc = 0.f;

#pragma unroll
    for (int cyi = 0; cyi < 2; ++cyi)
#pragma unroll
    for (int cxi = 0; cxi < 2; ++cxi) {
        const int t = (1 - cyi) * 2 + (1 - cxi);    // tap index, compile-time
        int lc = (py - ty0 + cyi) * NBX + (px - tx0 + cxi);
        int n = min(bcnt[lc], KB);
        for (int j = 0; j < n; ++j) {
            int e = lc * KB + j;
            float gx = bgx[e], gy = bgy[e], wgt = bwgt[e];
            float x0f = floorf(gx), y0f = floorf(gy);
            float tw;
            if constexpr (LVL == 0) {
                float x1f = x0f + 1.f, y1f = y0f + 1.f;
                tw = (t == 0) ? (x1f - gx) * (y1f - gy)
                   : (t == 1) ? (gx - x0f) * (y1f - gy)
                   : (t == 2) ? (x1f - gx) * (gy - y0f)
                              : (gx - x0f) * (gy - y0f);
            } else {
                float x1f = __fadd_rn(x0f, 1.0f), y1f = __fadd_rn(y0f, 1.0f);
                float dx0 = __fsub_rn(x1f, gx), dx1 = __fsub_rn(gx, x0f);
                float dy0 = __fsub_rn(y1f, gy), dy1 = __fsub_rn(gy, y0f);
                tw = (t == 0) ? __fmul_rn(dx0, dy0)
                   : (t == 1) ? __fmul_rn(dx1, dy0)
                   : (t == 2) ? __fmul_rn(dx0, dy1)
                              : __fmul_rn(dx1, dy1);
            }
            const float4* vp = nbp + (size_t)bsidx[e] * CBT4;
            if constexpr (LVL == 0) {
                float twv = tw * wgt;
                wacc += twv;
#pragma unroll
                for (int vi = 0; vi < NVM; ++vi) {
                    if (vi >= nv) break;
                    float4 q = vp[vi];
                    ax[vi] += q.x * twv; ay[vi] += q.y * twv;
                    az[vi] += q.z * twv; aw[vi] += q.w * twv;
                }
            } else {
                wacc += __fmul_rn(wgt, tw);
#pragma unroll
                for (int vi = 0; vi < NVM; ++vi) {
                    if (vi >= nv) break;
                    float4 q = vp[vi];
                    ax[vi] += __fmul_rn(__fmul_rn(q.x, wgt), tw);
                    ay[vi] += __fmul_rn(__fmul_rn(q.y, wgt), tw);
                    az[vi] += __fmul_rn(__fmul_rn(q.z, wgt), tw);
                    aw[vi] += __fmul_rn(__fmul_rn(q.w, wgt), tw);
                }
            }
        }
    }
    // overflow entries (expected ~0 at KB=10)
    int novr = min(s_ovn, OVCAP);
    for (int j = 0; j < novr; ++j) {
        if (atomicAdd(&ovlist[2 * j], 0) != s) continue;
        int sidx = atomicAdd(&ovlist[2 * j + 1], 0);
        gather_one<LVL, D, H, W, CBT4, NVM>(sidx, b, px, py, voff, nv,
            flow, met, a, scale, dly, dlx, nhwc, ax, ay, az, aw, wacc);
    }

    float denom = wacc + 1e-7f;
    size_t obase = ((size_t)b * Cout + cbase) * HW_ + (py * W + px);
#pragma unroll
    for (int vi = 0; vi < NVM; ++vi) {
        if (vi >= nv) break;
        int c0 = (voff + vi) * 4;
        if (c0 + 0 < CREAL) outp[obase + (size_t)(c0 + 0) * HW_] = ax[vi] / denom;
        if (c0 + 1 < CREAL) outp[obase + (size_t)(c0 + 1) * HW_] = ay[vi] / denom;
        if (c0 + 2 < CREAL) outp[obase + (size_t)(c0 + 2) * HW_] = az[vi] / denom;
        if (c0 + 3 < CREAL) outp[obase + (size_t)(c0 + 3) * HW_] = aw[vi] / denom;
    }
}

inline int nblk(long long n) { return (int)((n + 255) / 256); }

} // namespace

extern "C" void kernel_launch(void* const* d_in, const int* in_sizes, int n_in,
                              void* d_out, int out_size, void* d_ws, size_t ws_size,
                              hipStream_t stream) {
    const float* img1 = (const float*)d_in[0];
    const float* img2 = (const float*)d_in[1];
    const float* f1_1 = (const float*)d_in[2];
    const float* f1_2 = (const float*)d_in[3];
    const float* f1_3 = (const float*)d_in[4];
    const float* f2_1 = (const float*)d_in[5];
    const float* f2_2 = (const float*)d_in[6];
    const float* f2_3 = (const float*)d_in[7];
    const float* fl12 = (const float*)d_in[8];
    const float* fl21 = (const float*)d_in[9];
    const float* alpha = (const float*)d_in[10];
    float* out = (float*)d_out;

    const float dy1 = (float)(H0 - 1) / (float)(H1 - 1);
    const float dx1 = (float)(W0 - 1) / (float)(W1 - 1);
    const float dy2 = (float)(H0 - 1) / (float)(H2 - 1);
    const float dx2 = (float)(W0 - 1) / (float)(W2 - 1);

    // ---- workspace layout (NHWC buffers first, 16B-aligned) ----
    float* ws = (float*)d_ws;
    size_t o = 0;
    float* nh0a = ws + o; o += (size_t)Bn * HW0 * 36;
    float* nh0b = ws + o; o += (size_t)Bn * HW0 * 36;
    float* nh1a = ws + o; o += (size_t)Bn * HW1 * 64;
    float* nh1b = ws + o; o += (size_t)Bn * HW1 * 64;
    float* nh2a = ws + o; o += (size_t)Bn * HW2 * 96;
    float* nh2b = ws + o; o += (size_t)Bn * HW2 * 96;
    float* m12  = ws + o; o += (size_t)Bn * HW0;
    float* m21  = ws + o; o += (size_t)Bn * HW0;
    int* icnt   = (int*)(ws + o);                 // [0..2] irr, [3..5] ov
    int* irrl0  = icnt + 16;
    int* irrl1  = irrl0 + IRRCAP;
    int* irrl2  = irrl1 + IRRCAP;
    int* ovl0   = irrl2 + IRRCAP;                 // 2*OVCAP each
    int* ovl1   = ovl0 + 2 * OVCAP;
    int* ovl2   = ovl1 + 2 * OVCAP;

    float* l1 = out;
    float* l2 = l1 + (size_t)Bn * 70 * HW0;
    float* l3 = l2 + (size_t)Bn * 128 * HW1;

    (void)hipMemsetAsync(icnt, 0, 16 * sizeof(int), stream);

    // 1) metric (both dirs) + L0 irr detection
    metric2irr0_kernel<<<nblk((long long)2 * Bn * HW0), 256, 0, stream>>>(
        img1, img2, fl12, fl21, m12, m21, icnt + 0, irrl0);

    // 2) L1+L2 irr detection
    irr12_kernel<<<nblk((long long)2 * Bn * (HW1 + HW2)), 256, 0, stream>>>(
        fl12, fl21, icnt + 1, irrl1, icnt + 2, irrl2, dy1, dx1, dy2, dx2);

    // 3) all transposes
    TSegs ts;
    const int GT0 = Bn * HW0 / 128, GT1 = Bn * HW1 / 128, GT2 = Bn * HW2 / 128;
    ts.s0[0] = img1; ts.s1[0] = f1_1; ts.d[0] = nh0a; ts.C0[0] = 3;  ts.C1[0] = 32; ts.CH[0] = 36; ts.HW[0] = HW0;
    ts.s0[1] = img2; ts.s1[1] = f2_1; ts.d[1] = nh0b; ts.C0[1] = 3;  ts.C1[1] = 32; ts.CH[1] = 36; ts.HW[1] = HW0;
    ts.s0[2] = f1_2; ts.s1[2] = nullptr; ts.d[2] = nh1a; ts.C0[2] = 64; ts.C1[2] = 0; ts.CH[2] = 64; ts.HW[2] = HW1;
    ts.s0[3] = f2_2; ts.s1[3] = nullptr; ts.d[3] = nh1b; ts.C0[3] = 64; ts.C1[3] = 0; ts.CH[3] = 64; ts.HW[3] = HW1;
    ts.s0[4] = f1_3; ts.s1[4] = nullptr; ts.d[4] = nh2a; ts.C0[4] = 96; ts.C1[4] = 0; ts.CH[4] = 96; ts.HW[4] = HW2;
    ts.s0[5] = f2_3; ts.s1[5] = nullptr; ts.d[5] = nh2b; ts.C0[5] = 96; ts.C1[5] = 0; ts.CH[5] = 96; ts.HW[5] = HW2;
    ts.start[0] = 0;
    ts.start[1] = GT0;
    ts.start[2] = 2 * GT0;
    ts.start[3] = 2 * GT0 + GT1;
    ts.start[4] = 2 * GT0 + 2 * GT1;
    ts.start[5] = 2 * GT0 + 2 * GT1 + GT2;
    ts.start[6] = 2 * GT0 + 2 * GT1 + 2 * GT2;
    transpose_all_kernel<<<ts.start[6], 256, 0, stream>>>(ts);

    // 4-6) gathers (both dirs per level)
    const int GG0 = 2 * Bn * (H0 / 16) * (W0 / 16);   // 3584
    const int GG1 = 2 * Bn * (H1 / 16) * (W1 / 16);   // 896
    const int GG2 = 2 * Bn * (H2 / 16) * (W2 / 16);   // 224
    gather_kernel<0, 35, 9, 5, 4, 16, H0, W0><<<GG0, 512, 0, stream>>>(
        (const float4*)nh0a, (const float4*)nh0b, fl12, fl21, m12, m21, alpha,
        icnt + 0, irrl0, icnt + 3, ovl0, l1, 70, 0, 35, 0.f, 0.f, 0.f);
    gather_kernel<1, 64, 16, 8, 8, 8, H1, W1><<<GG1, 512, 0, stream>>>(
        (const float4*)nh1a, (const float4*)nh1b, fl12, fl21, m12, m21, alpha,
        icnt + 1, irrl1, icnt + 4, ovl1, l2, 128, 0, 64, 0.25f, dy1, dx1);
    gather_kernel<1, 96, 24, 12, 12, 8, H2, W2><<<GG2, 512, 0, stream>>>(
        (const float4*)nh2a, (const float4*)nh2b, fl12, fl21, m12, m21, alpha,
        icnt + 2, irrl2, icnt + 5, ovl2, l3, 192, 0, 96, 0.125f, dy2, dx2);
}